// Round 4
// baseline (410.837 us; speedup 1.0000x reference)
//
#include <hip/hip_runtime.h>
#include <stdint.h>

// SpatialSelfAttention: B=4, C=512, P=4096, 32 groups.
// Pipeline (all bf16 MFMA GEMMs are TN: A[M,K], B[N,K], K contiguous):
//   1. cvt weights fp32->bf16 (+ concat bq||bk); memset rsum=0
//   2. gn_stats + gn_norm -> h_t [B*P, C] bf16 (LDS tile transpose)
//   3. qk = h_t @ [wq;wk]^T  [B*P, 1024] (bias added)
//      v_c = wv @ h_t^T      [C, B*P]
//   4. P[b] = exp(q[b] @ k[b]^T * 1/sqrt(C))  [P,P] bf16 (UNNORMALIZED;
//      max-free exp is safe in fp32/bf16) + row sums via atomics
//   5. h_at[b] = (P[b] @ v_c[b]^T) * 1/rsum  [P, C]
//   6. out = wo @ h_at^T + bo + x  [C, B*P] fp32 == d_out layout
// Round 4: 32x32x16 MFMA everywhere (15% higher ceiling, half the MFMA
// instrs, 32-lane epilogue store segments). C/D: col=lane&31,
// row=(reg&3)+8*(reg>>2)+4*(lane>>5) [m74/m101]; A/B: m=l&31, k=(l>>5)*8+j.

typedef __bf16 bf16_t;
typedef __attribute__((ext_vector_type(8))) __bf16 bf16x8;
typedef __attribute__((ext_vector_type(16))) float floatx16;

constexpr int CDIM = 512;
constexpr int PDIM = 4096;

__device__ __forceinline__ void ld_g2l(const bf16_t* g, bf16_t* l) {
  __builtin_amdgcn_global_load_lds(
      (__attribute__((address_space(1))) void*)g,
      (__attribute__((address_space(3))) void*)l,
      16, 0, 0);
}

enum { EPI_QK = 0, EPI_V = 1, EPI_EXP = 2, EPI_PV = 3, EPI_OUT = 4 };

// TN GEMM: C[M,N] = A[M,K] * B[N,K]^T, TMx128 tile, BK=64, 256 threads,
// 32x32x16 bf16 MFMA. Waves 2x2 over (TM/2 x 64) quadrants.
// Grid: (N/128, M/TM, batch).
template <int EPI, int TM>
__global__ __launch_bounds__(256) void gemm_tn(
    const bf16_t* __restrict__ A, const bf16_t* __restrict__ B, int K,
    int lda, int ldb, long sAb, long sBb, long sCb, void* __restrict__ Cv,
    int ldc, const float* __restrict__ bias, const float* __restrict__ xres,
    float* __restrict__ rsum, float scale) {
  constexpr int MI = TM / 64;  // 32-row frags per wave quadrant
  __shared__ bf16_t Asm[TM * 64];
  __shared__ bf16_t Bsm[128 * 64];

  const int tid = threadIdx.x;
  const int w = tid >> 6, l = tid & 63;
  const int m0 = blockIdx.y * TM, n0 = blockIdx.x * 128;
  const int bz = blockIdx.z;

  const bf16_t* Ab = A + (long)bz * sAb + (long)m0 * lda;
  const bf16_t* Bb = B + (long)bz * sBb + (long)n0 * ldb;

  // staging: lane l of wave w loads 16B; LDS[r][slot] = global[r][slot^(r&7)]
  const int srow = 8 * w + (l >> 3);
  const int schunk = (l & 7) ^ (l >> 3);
  const bf16_t* ga = Ab + (long)srow * lda + schunk * 8;
  const bf16_t* gb = Bb + (long)srow * ldb + schunk * 8;
  bf16_t* lA = Asm + (8 * w) * 64;
  bf16_t* lB = Bsm + (8 * w) * 64;

  const int wr = w >> 1, wc = w & 1;
  const int col_l = l & 31, khalf = l >> 5, l7 = l & 7;

  floatx16 acc[MI][2];
#pragma unroll
  for (int i = 0; i < MI; i++)
#pragma unroll
    for (int j = 0; j < 2; j++)
#pragma unroll
      for (int e = 0; e < 16; e++) acc[i][j][e] = 0.f;

  for (int kb = 0; kb < K; kb += 64) {
#pragma unroll
    for (int p = 0; p < 4; p++) {
      if (p < TM / 32) ld_g2l(ga + (long)p * 32 * lda + kb, lA + p * 2048);
      ld_g2l(gb + (long)p * 32 * ldb + kb, lB + p * 2048);
    }
    __syncthreads();
#pragma unroll
    for (int ks = 0; ks < 4; ks++) {
      bf16x8 af[MI], bfv[2];
      const int sl = (((ks << 1) + khalf) ^ l7) * 8;  // swizzled elem offset
#pragma unroll
      for (int mi = 0; mi < MI; mi++) {
        int row = wr * (TM / 2) + mi * 32 + col_l;
        af[mi] = *(const bf16x8*)(Asm + row * 64 + sl);
      }
#pragma unroll
      for (int ni = 0; ni < 2; ni++) {
        int row = wc * 64 + ni * 32 + col_l;
        bfv[ni] = *(const bf16x8*)(Bsm + row * 64 + sl);
      }
#pragma unroll
      for (int mi = 0; mi < MI; mi++)
#pragma unroll
        for (int ni = 0; ni < 2; ni++)
          acc[mi][ni] = __builtin_amdgcn_mfma_f32_32x32x16_bf16(
              af[mi], bfv[ni], acc[mi][ni], 0, 0, 0);
    }
    __syncthreads();
  }

  // epilogue: C/D col=lane&31, row=(i&3)+8*(i>>2)+4*(lane>>5)
  const int rhalf = khalf * 4;
#pragma unroll
  for (int mi = 0; mi < MI; mi++) {
#pragma unroll
    for (int i = 0; i < 16; i++) {
      const int grow =
          m0 + wr * (TM / 2) + mi * 32 + (i & 3) + 8 * (i >> 2) + rhalf;
      float rowacc = 0.f;
      float inv = 0.f;
      if constexpr (EPI == EPI_PV)
        inv = __builtin_amdgcn_rcpf(bias[(long)bz * PDIM + grow]);
#pragma unroll
      for (int ni = 0; ni < 2; ni++) {
        const int gcol = n0 + wc * 64 + ni * 32 + col_l;
        float v = acc[mi][ni][i];
        if constexpr (EPI == EPI_QK) {
          v = v + bias[gcol];
          ((bf16_t*)Cv)[(long)bz * sCb + (long)grow * ldc + gcol] = (bf16_t)v;
        } else if constexpr (EPI == EPI_V) {
          v = v + bias[grow];
          ((bf16_t*)Cv)[(long)bz * sCb + (long)grow * ldc + gcol] = (bf16_t)v;
        } else if constexpr (EPI == EPI_EXP) {
          float p = __expf(v * scale);
          rowacc += p;
          ((bf16_t*)Cv)[(long)bz * sCb + (long)grow * ldc + gcol] = (bf16_t)p;
        } else if constexpr (EPI == EPI_PV) {
          v *= inv;
          ((bf16_t*)Cv)[(long)bz * sCb + (long)grow * ldc + gcol] = (bf16_t)v;
        } else {  // EPI_OUT: grow = out channel, gcol = b*P+p
          int ob = gcol >> 12, op = gcol & 4095;
          long o = ((long)ob * CDIM + grow) * PDIM + op;
          ((float*)Cv)[o] = v + bias[grow] + xres[o];
        }
      }
      if constexpr (EPI == EPI_EXP) {
        // reduce this row's 64-col partial across the 32 col-lanes
        // (lanes 0-31 and 32-63 hold different rows; xor<=16 stays inside)
        rowacc += __shfl_xor(rowacc, 1);
        rowacc += __shfl_xor(rowacc, 2);
        rowacc += __shfl_xor(rowacc, 4);
        rowacc += __shfl_xor(rowacc, 8);
        rowacc += __shfl_xor(rowacc, 16);
        if (col_l == 0) atomicAdd(&rsum[(long)bz * PDIM + grow], rowacc);
      }
    }
  }
}

// Stage 1: partial sums. Block i reads x[i*8192 .. +8192), writes (sum, sumsq).
__global__ __launch_bounds__(256) void gn_stats(const float* __restrict__ x,
                                                float2* __restrict__ part) {
  const int i = blockIdx.x;  // 1024 = B*G*8 slices, contiguous in x
  const float4* xp = (const float4*)(x + (long)i * 8192);
  float s0 = 0.f, s1 = 0.f;
  for (int j = threadIdx.x; j < 2048; j += 256) {
    float4 v = xp[j];
    s0 += v.x + v.y + v.z + v.w;
    s1 += v.x * v.x + v.y * v.y + v.z * v.z + v.w * v.w;
  }
  for (int o = 32; o; o >>= 1) {
    s0 += __shfl_xor(s0, o);
    s1 += __shfl_xor(s1, o);
  }
  __shared__ float r0[4], r1[4];
  if ((threadIdx.x & 63) == 0) {
    r0[threadIdx.x >> 6] = s0;
    r1[threadIdx.x >> 6] = s1;
  }
  __syncthreads();
  if (threadIdx.x == 0)
    part[i] = make_float2(r0[0] + r0[1] + r0[2] + r0[3],
                          r1[0] + r1[1] + r1[2] + r1[3]);
}

// Stage 2: normalize + transpose via LDS tile. Block = (b, 32 p-rows).
__global__ __launch_bounds__(256) void gn_norm(
    const float* __restrict__ x, const float* __restrict__ gamma,
    const float* __restrict__ beta, const float2* __restrict__ part,
    bf16_t* __restrict__ h_t) {
  const int b = blockIdx.x >> 7;
  const int p0 = (blockIdx.x & 127) * 32;
  const int t = threadIdx.x;
  __shared__ float gmS[512], btS[512];
  __shared__ float gmean[32], grstd[32];
  __shared__ __align__(16) bf16_t tile[32 * 520];

  if (t < 32) {
    const float2* pp = part + (b * 32 + t) * 8;
    float s0 = 0.f, s1 = 0.f;
#pragma unroll
    for (int s = 0; s < 8; s++) {
      float2 v = pp[s];
      s0 += v.x;
      s1 += v.y;
    }
    float mean = s0 * (1.f / 65536.f);
    float var = s1 * (1.f / 65536.f) - mean * mean;
    gmean[t] = mean;
    grstd[t] = rsqrtf(var + 1e-6f);
  }
  __syncthreads();
  for (int c = t; c < 512; c += 256) {
    float g = gamma[c] * grstd[c >> 4];
    gmS[c] = g;
    btS[c] = beta[c] - gmean[c >> 4] * g;
  }
  __syncthreads();

  const int cc = t >> 3, pcol = (t & 7) * 4;
  for (int pass = 0; pass < 16; pass++) {
    int c = pass * 32 + cc;
    float4 v = *(const float4*)(x + ((long)(b * 512 + c)) * 4096 + p0 + pcol);
    float g = gmS[c], bb = btS[c];
    tile[(pcol + 0) * 520 + c] = (bf16_t)(v.x * g + bb);
    tile[(pcol + 1) * 520 + c] = (bf16_t)(v.y * g + bb);
    tile[(pcol + 2) * 520 + c] = (bf16_t)(v.z * g + bb);
    tile[(pcol + 3) * 520 + c] = (bf16_t)(v.w * g + bb);
  }
  __syncthreads();
  const int p = t >> 3;
  bf16_t* orow = h_t + ((long)(b * 4096 + p0 + p)) * 512;
  const bf16_t* trow = tile + p * 520;
#pragma unroll
  for (int j = 0; j < 8; j++) {
    int ch = (t & 7) + 8 * j;
    *(uint4*)(orow + ch * 8) = *(const uint4*)(trow + ch * 8);
  }
}

__global__ __launch_bounds__(256) void cvt_weights(
    const float* __restrict__ wq, const float* __restrict__ wk,
    const float* __restrict__ wv, const float* __restrict__ wo,
    const float* __restrict__ bq, const float* __restrict__ bk,
    bf16_t* __restrict__ out, float* __restrict__ bqk) {
  int i = blockIdx.x * 256 + threadIdx.x;  // 262144 elements each
  out[i] = (bf16_t)wq[i];
  out[262144 + i] = (bf16_t)wk[i];
  out[2 * 262144 + i] = (bf16_t)wv[i];
  out[3 * 262144 + i] = (bf16_t)wo[i];
  if (i < 512)
    bqk[i] = bq[i];
  else if (i < 1024)
    bqk[i] = bk[i - 512];
}

extern "C" void kernel_launch(void* const* d_in, const int* in_sizes, int n_in,
                              void* d_out, int out_size, void* d_ws,
                              size_t ws_size, hipStream_t stream) {
  const float* x = (const float*)d_in[0];
  const float* gamma = (const float*)d_in[1];
  const float* beta = (const float*)d_in[2];
  const float* wq = (const float*)d_in[3];
  const float* bq = (const float*)d_in[4];
  const float* wk = (const float*)d_in[5];
  const float* bk = (const float*)d_in[6];
  const float* wv = (const float*)d_in[7];
  const float* bv = (const float*)d_in[8];
  const float* wo = (const float*)d_in[9];
  const float* bo = (const float*)d_in[10];

  char* ws = (char*)d_ws;
  bf16_t* h_t = (bf16_t*)(ws);                  // [16384,512]       @0
  bf16_t* qk = (bf16_t*)(ws + (16l << 20));     // [16384,1024]      @16MB
  bf16_t* v_c = (bf16_t*)(ws + (48l << 20));    // [512,16384]       @48MB
  bf16_t* h_at = (bf16_t*)(ws + (64l << 20));   // [16384,512]       @64MB
  bf16_t* w_b = (bf16_t*)(ws + (80l << 20));    // 4x[512,512]       @80MB
  float2* part = (float2*)(ws + (83l << 20));   // [1024] partials   @83MB
  float* bqk = (float*)(ws + (83l << 20) + (64l << 10));   // [1024]
  float* rsum = (float*)(ws + (83l << 20) + (128l << 10)); // [4*4096]
  bf16_t* Sbuf = (bf16_t*)(ws + (84l << 20));   // [4,4096,4096]     @84MB

  const long sP = (long)PDIM * CDIM;   // 2097152
  const long sQK = (long)PDIM * 1024;  // 4194304
  const long sS = (long)PDIM * PDIM;   // 16777216
  const float qscale = 0.04419417382415922f;  // 1/sqrt(512)

  hipMemsetAsync(rsum, 0, 4 * PDIM * sizeof(float), stream);
  cvt_weights<<<1024, 256, 0, stream>>>(wq, wk, wv, wo, bq, bk, w_b, bqk);
  gn_stats<<<1024, 256, 0, stream>>>(x, part);
  gn_norm<<<512, 256, 0, stream>>>(x, gamma, beta, part, h_t);
  // fused q|k projection: B = [wq;wk] rows 0..1023, bias bqk
  gemm_tn<EPI_QK, 128><<<dim3(8, 128, 1), 256, 0, stream>>>(
      h_t, w_b, 512, 512, 512, 0, 0, 0, qk, 1024, bqk, nullptr, nullptr, 1.0f);
  gemm_tn<EPI_V, 64><<<dim3(128, 8, 1), 256, 0, stream>>>(
      w_b + 2 * 262144, h_t, 512, 512, 512, 0, 0, 0, v_c, 16384, bv, nullptr,
      nullptr, 1.0f);
  // P = exp(q k^T / sqrt(C)) (unnormalized) + row sums into rsum
  gemm_tn<EPI_EXP, 128><<<dim3(32, 32, 4), 256, 0, stream>>>(
      qk, qk + 512, 512, 1024, 1024, sQK, sQK, sS, Sbuf, 4096, nullptr,
      nullptr, rsum, qscale);
  // h_at = (P @ v^T) / rsum
  gemm_tn<EPI_PV, 64><<<dim3(4, 64, 4), 256, 0, stream>>>(
      Sbuf, v_c, 4096, 4096, 16384, sS, (long)PDIM, sP, h_at, 512, rsum,
      nullptr, nullptr, 1.0f);
  gemm_tn<EPI_OUT, 64><<<dim3(128, 8, 1), 256, 0, stream>>>(
      w_b + 3 * 262144, h_at, 512, 512, 512, 0, 0, 0, d_out, 4096, bo, x,
      nullptr, 1.0f);
}

// Round 5
// 345.717 us; speedup vs baseline: 1.1884x; 1.1884x over previous
//
#include <hip/hip_runtime.h>
#include <stdint.h>

// SpatialSelfAttention: B=4, C=512, P=4096, 32 groups.
// Pipeline:
//   1. cvt weights fp32->bf16 (+ concat bq||bk); memset rsum=0
//   2. gn_stats + gn_norm -> h_t [B*P, C] bf16 (LDS tile transpose)
//   3. qk = h_t @ [wq;wk]^T  [B*P, 1024] bf16 (bias added)
//      v_c = wv @ h_t^T      [C, B*P]  ** fp8 e4m3 **
//   4. P[b] = exp(q[b] @ k[b]^T / sqrt(C))  [P,P] ** fp8 e4m3 ** (unnormalized,
//      P in [~0.3,3.3] fits e4m3; row sums (fp32, pre-quant) via atomics)
//   5. h_at[b] = (P[b] @ v_c[b]^T) / rsum  [P, C] bf16 via MX-scaled
//      mfma_scale_f32_16x16x128_f8f6f4 (unit scales) — 2x MFMA rate, half bytes
//   6. out = wo @ h_at^T + bo + x  [C, B*P] fp32 == d_out layout
// Round 5: reverted 32x32 MFMA (round-4: 8.4M LDS bank conflicts, -39 us);
// back to the 16x16x32 conflict-free pattern everywhere bf16 is used.

typedef __bf16 bf16_t;
typedef __attribute__((ext_vector_type(8))) __bf16 bf16x8;
typedef __attribute__((ext_vector_type(4))) float floatx4;
typedef __attribute__((ext_vector_type(8))) int intx8;

constexpr int CDIM = 512;
constexpr int PDIM = 4096;

__device__ __forceinline__ void ld_g2l(const void* g, void* l) {
  __builtin_amdgcn_global_load_lds(
      (const __attribute__((address_space(1))) void*)g,
      (__attribute__((address_space(3))) void*)l,
      16, 0, 0);
}

__device__ __forceinline__ uint8_t f32_to_fp8(float v) {
  int r = __builtin_amdgcn_cvt_pk_fp8_f32(v, v, 0, false);
  return (uint8_t)(r & 0xff);
}

enum { EPI_QK = 0, EPI_V = 1, EPI_EXP = 2, EPI_OUT = 4 };

// TN GEMM (bf16): C[M,N] = A[M,K] * B[N,K]^T, TMx128 tile, BK=64, 256 thr,
// 16x16x32 MFMA (round-3 verified conflict-free pattern).
template <int EPI, int TM>
__global__ __launch_bounds__(256) void gemm_tn(
    const bf16_t* __restrict__ A, const bf16_t* __restrict__ B, int K,
    int lda, int ldb, long sAb, long sBb, long sCb, void* __restrict__ Cv,
    int ldc, const float* __restrict__ bias, const float* __restrict__ xres,
    float* __restrict__ rsum, float scale) {
  constexpr int MI = TM / 32;
  constexpr int WROWS = TM / 2;
  __shared__ bf16_t Asm[TM * 64];
  __shared__ bf16_t Bsm[128 * 64];

  const int tid = threadIdx.x;
  const int w = tid >> 6, l = tid & 63;
  const int m0 = blockIdx.y * TM, n0 = blockIdx.x * 128;
  const int bz = blockIdx.z;

  const bf16_t* Ab = A + (long)bz * sAb + (long)m0 * lda;
  const bf16_t* Bb = B + (long)bz * sBb + (long)n0 * ldb;

  const int srow = 8 * w + (l >> 3);
  const int schunk = (l & 7) ^ (l >> 3);
  const bf16_t* ga = Ab + (long)srow * lda + schunk * 8;
  const bf16_t* gb = Bb + (long)srow * ldb + schunk * 8;
  bf16_t* lA = Asm + (8 * w) * 64;
  bf16_t* lB = Bsm + (8 * w) * 64;

  const int wr = w >> 1, wc = w & 1;
  const int fr = l & 15, fq = l >> 4, l7 = l & 7;

  floatx4 acc[MI][4];
  floatx4 zz = {0.f, 0.f, 0.f, 0.f};
#pragma unroll
  for (int i = 0; i < MI; i++)
#pragma unroll
    for (int j = 0; j < 4; j++) acc[i][j] = zz;

  for (int kb = 0; kb < K; kb += 64) {
#pragma unroll
    for (int p = 0; p < 4; p++) {
      if (p < TM / 32) ld_g2l(ga + (long)p * 32 * lda + kb, lA + p * 2048);
      ld_g2l(gb + (long)p * 32 * ldb + kb, lB + p * 2048);
    }
    __syncthreads();
#pragma unroll
    for (int ks = 0; ks < 2; ks++) {
      bf16x8 af[MI], bfv[4];
      const int ch = (ks * 4 + fq);
#pragma unroll
      for (int mi = 0; mi < MI; mi++) {
        int row = wr * WROWS + mi * 16 + fr;
        af[mi] = *(const bf16x8*)(Asm + row * 64 + ((ch ^ l7) * 8));
      }
#pragma unroll
      for (int ni = 0; ni < 4; ni++) {
        int row = wc * 64 + ni * 16 + fr;
        bfv[ni] = *(const bf16x8*)(Bsm + row * 64 + ((ch ^ l7) * 8));
      }
#pragma unroll
      for (int mi = 0; mi < MI; mi++)
#pragma unroll
        for (int ni = 0; ni < 4; ni++)
          acc[mi][ni] = __builtin_amdgcn_mfma_f32_16x16x32_bf16(
              af[mi], bfv[ni], acc[mi][ni], 0, 0, 0);
    }
    __syncthreads();
  }

  // epilogue: C/D frag mapping col=lane&15, row=(lane>>4)*4+i (m89-verified)
  const int rb = fq * 4;
#pragma unroll
  for (int mi = 0; mi < MI; mi++) {
#pragma unroll
    for (int i = 0; i < 4; i++) {
      const int grow = m0 + wr * WROWS + mi * 16 + rb + i;
      float rowacc = 0.f;
#pragma unroll
      for (int ni = 0; ni < 4; ni++) {
        const int gcol = n0 + wc * 64 + ni * 16 + fr;
        float v = acc[mi][ni][i];
        if constexpr (EPI == EPI_QK) {
          v = v + bias[gcol];
          ((bf16_t*)Cv)[(long)bz * sCb + (long)grow * ldc + gcol] = (bf16_t)v;
        } else if constexpr (EPI == EPI_V) {
          v = v + bias[grow];
          ((uint8_t*)Cv)[(long)bz * sCb + (long)grow * ldc + gcol] =
              f32_to_fp8(v);
        } else if constexpr (EPI == EPI_EXP) {
          float p = __expf(v * scale);
          rowacc += p;
          ((uint8_t*)Cv)[(long)bz * sCb + (long)grow * ldc + gcol] =
              f32_to_fp8(p);
        } else {  // EPI_OUT: grow = out channel, gcol = b*P+p
          int ob = gcol >> 12, op = gcol & 4095;
          long o = ((long)ob * CDIM + grow) * PDIM + op;
          ((float*)Cv)[o] = v + bias[grow] + xres[o];
        }
      }
      if constexpr (EPI == EPI_EXP) {
        rowacc += __shfl_xor(rowacc, 1);
        rowacc += __shfl_xor(rowacc, 2);
        rowacc += __shfl_xor(rowacc, 4);
        rowacc += __shfl_xor(rowacc, 8);
        if (fr == 0) atomicAdd(&rsum[(long)bz * PDIM + grow], rowacc);
      }
    }
  }
}

// PV with MX-fp8: h_at[b] = (P[b] @ v_c[b]^T)/rsum. 64x128 tile, BK=128,
// mfma_scale_f32_16x16x128_f8f6f4 with unit e8m0 scales (127).
// Grid (4, 64, 4). A = S fp8 [4096,4096]/batch, B = v_c fp8 [512,16384].
__global__ __launch_bounds__(256) void gemm_pv_mx(
    const uint8_t* __restrict__ S, const uint8_t* __restrict__ V,
    const float* __restrict__ rsum, bf16_t* __restrict__ H) {
  __shared__ uint8_t Asm[64 * 128];
  __shared__ uint8_t Bsm[128 * 128];

  const int tid = threadIdx.x;
  const int w = tid >> 6, l = tid & 63;
  const int m0 = blockIdx.y * 64, n0 = blockIdx.x * 128;
  const int bz = blockIdx.z;

  const uint8_t* Ab = S + (long)bz * 16777216 + (long)m0 * 4096;
  const uint8_t* Bb = V + (long)bz * 4096 + (long)n0 * 16384;

  // staging: 256 thr x 16B = 32 rows (128B/row) per pass; swizzle slot^(row&7)
  const int srow = 8 * w + (l >> 3);
  const int schunk = (l & 7) ^ (l >> 3);
  const uint8_t* ga = Ab + (long)srow * 4096 + schunk * 16;
  const uint8_t* gb = Bb + (long)srow * 16384 + schunk * 16;
  uint8_t* lA = Asm + (8 * w) * 128;
  uint8_t* lB = Bsm + (8 * w) * 128;

  const int wr = w >> 1, wc = w & 1;  // wave quadrant: 32 rows x 64 cols
  const int fr = l & 15, fq = l >> 4, l7 = l & 7;

  floatx4 acc[2][4];
#pragma unroll
  for (int i = 0; i < 2; i++)
#pragma unroll
    for (int j = 0; j < 4; j++) acc[i][j] = floatx4{0.f, 0.f, 0.f, 0.f};

  // lane reads k-bytes [fq*32, fq*32+31] = chunks 2fq, 2fq+1 (16B each)
  const int s0 = ((2 * fq) ^ l7) * 16;
  const int s1 = ((2 * fq + 1) ^ l7) * 16;

  for (int kb = 0; kb < 4096; kb += 128) {
#pragma unroll
    for (int p = 0; p < 4; p++) {
      if (p < 2) ld_g2l(ga + (long)p * 32 * 4096 + kb, lA + p * 4096);
      ld_g2l(gb + (long)p * 32 * 16384 + kb, lB + p * 4096);
    }
    __syncthreads();

    intx8 af[2];
#pragma unroll
    for (int mi = 0; mi < 2; mi++) {
      const uint8_t* base = Asm + (wr * 32 + mi * 16 + fr) * 128;
      uint4 x0 = *(const uint4*)(base + s0);
      uint4 x1 = *(const uint4*)(base + s1);
      af[mi] = intx8{(int)x0.x, (int)x0.y, (int)x0.z, (int)x0.w,
                     (int)x1.x, (int)x1.y, (int)x1.z, (int)x1.w};
    }
#pragma unroll
    for (int ni = 0; ni < 4; ni++) {
      const uint8_t* base = Bsm + (wc * 64 + ni * 16 + fr) * 128;
      uint4 y0 = *(const uint4*)(base + s0);
      uint4 y1 = *(const uint4*)(base + s1);
      intx8 bf = intx8{(int)y0.x, (int)y0.y, (int)y0.z, (int)y0.w,
                       (int)y1.x, (int)y1.y, (int)y1.z, (int)y1.w};
#pragma unroll
      for (int mi = 0; mi < 2; mi++)
        acc[mi][ni] = __builtin_amdgcn_mfma_scale_f32_16x16x128_f8f6f4(
            af[mi], bf, acc[mi][ni], 0, 0, 0, 127, 0, 127);
    }
    __syncthreads();
  }

  const int rb = fq * 4;
#pragma unroll
  for (int mi = 0; mi < 2; mi++) {
#pragma unroll
    for (int i = 0; i < 4; i++) {
      const int grow = m0 + wr * 32 + mi * 16 + rb + i;
      const float inv = __builtin_amdgcn_rcpf(rsum[(long)bz * PDIM + grow]);
#pragma unroll
      for (int ni = 0; ni < 4; ni++) {
        const int gcol = n0 + wc * 64 + ni * 16 + fr;
        H[(long)bz * (PDIM * CDIM) + (long)grow * CDIM + gcol] =
            (bf16_t)(acc[mi][ni][i] * inv);
      }
    }
  }
}

// Stage 1: partial sums. Block i reads x[i*8192 .. +8192), writes (sum, sumsq).
__global__ __launch_bounds__(256) void gn_stats(const float* __restrict__ x,
                                                float2* __restrict__ part) {
  const int i = blockIdx.x;
  const float4* xp = (const float4*)(x + (long)i * 8192);
  float s0 = 0.f, s1 = 0.f;
  for (int j = threadIdx.x; j < 2048; j += 256) {
    float4 v = xp[j];
    s0 += v.x + v.y + v.z + v.w;
    s1 += v.x * v.x + v.y * v.y + v.z * v.z + v.w * v.w;
  }
  for (int o = 32; o; o >>= 1) {
    s0 += __shfl_xor(s0, o);
    s1 += __shfl_xor(s1, o);
  }
  __shared__ float r0[4], r1[4];
  if ((threadIdx.x & 63) == 0) {
    r0[threadIdx.x >> 6] = s0;
    r1[threadIdx.x >> 6] = s1;
  }
  __syncthreads();
  if (threadIdx.x == 0)
    part[i] = make_float2(r0[0] + r0[1] + r0[2] + r0[3],
                          r1[0] + r1[1] + r1[2] + r1[3]);
}

// Stage 2: normalize + transpose via LDS tile. Block = (b, 32 p-rows).
__global__ __launch_bounds__(256) void gn_norm(
    const float* __restrict__ x, const float* __restrict__ gamma,
    const float* __restrict__ beta, const float2* __restrict__ part,
    bf16_t* __restrict__ h_t) {
  const int b = blockIdx.x >> 7;
  const int p0 = (blockIdx.x & 127) * 32;
  const int t = threadIdx.x;
  __shared__ float gmS[512], btS[512];
  __shared__ float gmean[32], grstd[32];
  __shared__ __align__(16) bf16_t tile[32 * 520];

  if (t < 32) {
    const float2* pp = part + (b * 32 + t) * 8;
    float s0 = 0.f, s1 = 0.f;
#pragma unroll
    for (int s = 0; s < 8; s++) {
      float2 v = pp[s];
      s0 += v.x;
      s1 += v.y;
    }
    float mean = s0 * (1.f / 65536.f);
    float var = s1 * (1.f / 65536.f) - mean * mean;
    gmean[t] = mean;
    grstd[t] = rsqrtf(var + 1e-6f);
  }
  __syncthreads();
  for (int c = t; c < 512; c += 256) {
    float g = gamma[c] * grstd[c >> 4];
    gmS[c] = g;
    btS[c] = beta[c] - gmean[c >> 4] * g;
  }
  __syncthreads();

  const int cc = t >> 3, pcol = (t & 7) * 4;
  for (int pass = 0; pass < 16; pass++) {
    int c = pass * 32 + cc;
    float4 v = *(const float4*)(x + ((long)(b * 512 + c)) * 4096 + p0 + pcol);
    float g = gmS[c], bb = btS[c];
    tile[(pcol + 0) * 520 + c] = (bf16_t)(v.x * g + bb);
    tile[(pcol + 1) * 520 + c] = (bf16_t)(v.y * g + bb);
    tile[(pcol + 2) * 520 + c] = (bf16_t)(v.z * g + bb);
    tile[(pcol + 3) * 520 + c] = (bf16_t)(v.w * g + bb);
  }
  __syncthreads();
  const int p = t >> 3;
  bf16_t* orow = h_t + ((long)(b * 4096 + p0 + p)) * 512;
  const bf16_t* trow = tile + p * 520;
#pragma unroll
  for (int j = 0; j < 8; j++) {
    int ch = (t & 7) + 8 * j;
    *(uint4*)(orow + ch * 8) = *(const uint4*)(trow + ch * 8);
  }
}

__global__ __launch_bounds__(256) void cvt_weights(
    const float* __restrict__ wq, const float* __restrict__ wk,
    const float* __restrict__ wv, const float* __restrict__ wo,
    const float* __restrict__ bq, const float* __restrict__ bk,
    bf16_t* __restrict__ out, float* __restrict__ bqk) {
  int i = blockIdx.x * 256 + threadIdx.x;
  out[i] = (bf16_t)wq[i];
  out[262144 + i] = (bf16_t)wk[i];
  out[2 * 262144 + i] = (bf16_t)wv[i];
  out[3 * 262144 + i] = (bf16_t)wo[i];
  if (i < 512)
    bqk[i] = bq[i];
  else if (i < 1024)
    bqk[i] = bk[i - 512];
}

extern "C" void kernel_launch(void* const* d_in, const int* in_sizes, int n_in,
                              void* d_out, int out_size, void* d_ws,
                              size_t ws_size, hipStream_t stream) {
  const float* x = (const float*)d_in[0];
  const float* gamma = (const float*)d_in[1];
  const float* beta = (const float*)d_in[2];
  const float* wq = (const float*)d_in[3];
  const float* bq = (const float*)d_in[4];
  const float* wk = (const float*)d_in[5];
  const float* bk = (const float*)d_in[6];
  const float* wv = (const float*)d_in[7];
  const float* bv = (const float*)d_in[8];
  const float* wo = (const float*)d_in[9];
  const float* bo = (const float*)d_in[10];

  char* ws = (char*)d_ws;
  bf16_t* h_t = (bf16_t*)(ws);                  // [16384,512] bf16  @0
  bf16_t* qk = (bf16_t*)(ws + (16l << 20));     // [16384,1024] bf16 @16MB
  uint8_t* v_c = (uint8_t*)(ws + (48l << 20));  // [512,16384] fp8   @48MB
  bf16_t* h_at = (bf16_t*)(ws + (64l << 20));   // [16384,512] bf16  @64MB
  bf16_t* w_b = (bf16_t*)(ws + (80l << 20));    // 4x[512,512] bf16  @80MB
  float2* part = (float2*)(ws + (83l << 20));   // [1024] partials   @83MB
  float* bqk = (float*)(ws + (83l << 20) + (64l << 10));    // [1024]
  float* rsum = (float*)(ws + (83l << 20) + (128l << 10));  // [4*4096]
  uint8_t* Sbuf = (uint8_t*)(ws + (84l << 20)); // [4,4096,4096] fp8 @84MB

  const long sP = (long)PDIM * CDIM;   // 2097152
  const long sQK = (long)PDIM * 1024;  // 4194304
  const long sS = (long)PDIM * PDIM;   // 16777216
  const float qscale = 0.04419417382415922f;  // 1/sqrt(512)

  hipMemsetAsync(rsum, 0, 4 * PDIM * sizeof(float), stream);
  cvt_weights<<<1024, 256, 0, stream>>>(wq, wk, wv, wo, bq, bk, w_b, bqk);
  gn_stats<<<1024, 256, 0, stream>>>(x, part);
  gn_norm<<<512, 256, 0, stream>>>(x, gamma, beta, part, h_t);
  // fused q|k projection: B = [wq;wk] rows 0..1023, bias bqk
  gemm_tn<EPI_QK, 128><<<dim3(8, 128, 1), 256, 0, stream>>>(
      h_t, w_b, 512, 512, 512, 0, 0, 0, qk, 1024, bqk, nullptr, nullptr, 1.0f);
  gemm_tn<EPI_V, 64><<<dim3(128, 8, 1), 256, 0, stream>>>(
      w_b + 2 * 262144, h_t, 512, 512, 512, 0, 0, 0, v_c, 16384, bv, nullptr,
      nullptr, 1.0f);
  // P = exp(q k^T / sqrt(C)) fp8 (unnormalized) + fp32 row sums into rsum
  gemm_tn<EPI_EXP, 128><<<dim3(32, 32, 4), 256, 0, stream>>>(
      qk, qk + 512, 512, 1024, 1024, sQK, sQK, sS, Sbuf, 4096, nullptr,
      nullptr, rsum, qscale);
  // h_at = (P @ v^T) / rsum  — MX-fp8 K=128 MFMA
  gemm_pv_mx<<<dim3(4, 64, 4), 256, 0, stream>>>(Sbuf, v_c, rsum, h_at);
  gemm_tn<EPI_OUT, 64><<<dim3(128, 8, 1), 256, 0, stream>>>(
      w_b + 3 * 262144, h_at, 512, 512, 512, 0, 0, 0, d_out, 4096, bo, x,
      nullptr, 1.0f);
}

// Round 6
// 326.512 us; speedup vs baseline: 1.2583x; 1.0588x over previous
//
#include <hip/hip_runtime.h>
#include <stdint.h>

// SpatialSelfAttention: B=4, C=512, P=4096, 32 groups.
// Pipeline:
//   1. cvt weights fp32->bf16 (+ concat bq||bk); memset rsum=0
//   2. gn_stats + gn_norm -> h_t [B*P, C] bf16 (LDS tile transpose)
//   3. qk = h_t @ [wq;wk]^T  [B*P, 1024] bf16 (bias added)
//      v_c = wv @ h_t^T      [C, B*P]  fp8 e4m3
//   4. P[b] = exp(q[b] @ k[b]^T / sqrt(C))  [P,P] fp8 e4m3 (unnormalized;
//      fp32 row sums via atomics)
//   5. h_at[b] = (P[b] @ v_c[b]^T) / rsum  [P, C] bf16 via MX-scaled
//      mfma_scale_f32_16x16x128_f8f6f4 (unit scales)
//   6. out = wo @ h_at^T + bo + x  [C, B*P] fp32 == d_out layout
// Round 6: COLUMN-INTERLEAVED B-fragments — MFMA #ni covers global cols
// {4t+ni}, so each lane's 4 ni-values are 4 CONSECUTIVE columns ->
// every epilogue packs 4 elements into one dword/bf16x4/float4 store
// (round-5 fp8 epilogue was 64 scalar byte-stores/lane = the regression).
// Bank pattern unchanged (row stride 128B == 0 mod 32 banks).

typedef __bf16 bf16_t;
typedef __attribute__((ext_vector_type(4))) __bf16 bf16x4;
typedef __attribute__((ext_vector_type(8))) __bf16 bf16x8;
typedef __attribute__((ext_vector_type(4))) float floatx4;
typedef __attribute__((ext_vector_type(8))) int intx8;

constexpr int CDIM = 512;
constexpr int PDIM = 4096;

__device__ __forceinline__ void ld_g2l(const void* g, void* l) {
  __builtin_amdgcn_global_load_lds(
      (const __attribute__((address_space(1))) void*)g,
      (__attribute__((address_space(3))) void*)l,
      16, 0, 0);
}

__device__ __forceinline__ uint32_t pk_fp8x4(float a, float b, float c,
                                             float d) {
  int r = __builtin_amdgcn_cvt_pk_fp8_f32(a, b, 0, false);
  r = __builtin_amdgcn_cvt_pk_fp8_f32(c, d, r, true);
  return (uint32_t)r;
}

enum { EPI_QK = 0, EPI_V = 1, EPI_EXP = 2, EPI_OUT = 4 };

// TN GEMM (bf16): C[M,N] = A[M,K] * B[N,K]^T, TMx128 tile, BK=64, 256 thr,
// 16x16x32 MFMA, column-interleaved B-frags (see header).
template <int EPI, int TM>
__global__ __launch_bounds__(256) void gemm_tn(
    const bf16_t* __restrict__ A, const bf16_t* __restrict__ B, int K,
    int lda, int ldb, long sAb, long sBb, long sCb, void* __restrict__ Cv,
    int ldc, const float* __restrict__ bias, const float* __restrict__ xres,
    float* __restrict__ rsum, float scale) {
  constexpr int MI = TM / 32;
  constexpr int WROWS = TM / 2;
  __shared__ bf16_t Asm[TM * 64];
  __shared__ bf16_t Bsm[128 * 64];

  const int tid = threadIdx.x;
  const int w = tid >> 6, l = tid & 63;
  const int m0 = blockIdx.y * TM, n0 = blockIdx.x * 128;
  const int bz = blockIdx.z;

  const bf16_t* Ab = A + (long)bz * sAb + (long)m0 * lda;
  const bf16_t* Bb = B + (long)bz * sBb + (long)n0 * ldb;

  const int srow = 8 * w + (l >> 3);
  const int schunk = (l & 7) ^ (l >> 3);
  const bf16_t* ga = Ab + (long)srow * lda + schunk * 8;
  const bf16_t* gb = Bb + (long)srow * ldb + schunk * 8;
  bf16_t* lA = Asm + (8 * w) * 64;
  bf16_t* lB = Bsm + (8 * w) * 64;

  const int wr = w >> 1, wc = w & 1;
  const int fr = l & 15, fq = l >> 4, l7 = l & 7;

  floatx4 acc[MI][4];
  floatx4 zz = {0.f, 0.f, 0.f, 0.f};
#pragma unroll
  for (int i = 0; i < MI; i++)
#pragma unroll
    for (int j = 0; j < 4; j++) acc[i][j] = zz;

  for (int kb = 0; kb < K; kb += 64) {
#pragma unroll
    for (int p = 0; p < 4; p++) {
      if (p < TM / 32) ld_g2l(ga + (long)p * 32 * lda + kb, lA + p * 2048);
      ld_g2l(gb + (long)p * 32 * ldb + kb, lB + p * 2048);
    }
    __syncthreads();
#pragma unroll
    for (int ks = 0; ks < 2; ks++) {
      bf16x8 af[MI], bfv[4];
      const int ch = (ks * 4 + fq);
#pragma unroll
      for (int mi = 0; mi < MI; mi++) {
        int row = wr * WROWS + mi * 16 + fr;
        af[mi] = *(const bf16x8*)(Asm + row * 64 + ((ch ^ l7) * 8));
      }
#pragma unroll
      for (int ni = 0; ni < 4; ni++) {
        int row = wc * 64 + ni + 4 * fr;  // interleaved: MFMA ni = cols 4t+ni
        bfv[ni] = *(const bf16x8*)(Bsm + row * 64 + ((ch ^ l7) * 8));
      }
#pragma unroll
      for (int mi = 0; mi < MI; mi++)
#pragma unroll
        for (int ni = 0; ni < 4; ni++)
          acc[mi][ni] = __builtin_amdgcn_mfma_f32_16x16x32_bf16(
              af[mi], bfv[ni], acc[mi][ni], 0, 0, 0);
    }
    __syncthreads();
  }

  // epilogue: C/D row=(lane>>4)*4+i; lane's 4 ni = 4 consecutive cols
  const int rb = fq * 4;
  const int gcolb = n0 + wc * 64 + 4 * fr;
#pragma unroll
  for (int mi = 0; mi < MI; mi++) {
#pragma unroll
    for (int i = 0; i < 4; i++) {
      const int grow = m0 + wr * WROWS + mi * 16 + rb + i;
      float v0 = acc[mi][0][i], v1 = acc[mi][1][i];
      float v2 = acc[mi][2][i], v3 = acc[mi][3][i];
      if constexpr (EPI == EPI_QK) {
        const float4 b4 = *(const float4*)(bias + gcolb);
        bf16x4 o = {(bf16_t)(v0 + b4.x), (bf16_t)(v1 + b4.y),
                    (bf16_t)(v2 + b4.z), (bf16_t)(v3 + b4.w)};
        *(bf16x4*)((bf16_t*)Cv + (long)bz * sCb + (long)grow * ldc + gcolb) =
            o;
      } else if constexpr (EPI == EPI_V) {
        const float bb = bias[grow];
        uint32_t d = pk_fp8x4(v0 + bb, v1 + bb, v2 + bb, v3 + bb);
        *(uint32_t*)((uint8_t*)Cv + (long)bz * sCb + (long)grow * ldc +
                     gcolb) = d;
      } else if constexpr (EPI == EPI_EXP) {
        // scale = 1/sqrt(C) * log2(e); exp2 saves the inner mul
        float p0 = exp2f(v0 * scale), p1 = exp2f(v1 * scale);
        float p2 = exp2f(v2 * scale), p3 = exp2f(v3 * scale);
        *(uint32_t*)((uint8_t*)Cv + (long)bz * sCb + (long)grow * ldc +
                     gcolb) = pk_fp8x4(p0, p1, p2, p3);
        float rowacc = (p0 + p1) + (p2 + p3);
        rowacc += __shfl_xor(rowacc, 1);
        rowacc += __shfl_xor(rowacc, 2);
        rowacc += __shfl_xor(rowacc, 4);
        rowacc += __shfl_xor(rowacc, 8);
        if (fr == 0) atomicAdd(&rsum[(long)bz * PDIM + grow], rowacc);
      } else {  // EPI_OUT: grow = out channel, gcolb = b*P+p (4-aligned)
        int ob = gcolb >> 12, op = gcolb & 4095;
        long o = ((long)ob * CDIM + grow) * PDIM + op;
        const float4 xr = *(const float4*)(xres + o);
        const float bb = bias[grow];
        float4 ov = {v0 + bb + xr.x, v1 + bb + xr.y, v2 + bb + xr.z,
                     v3 + bb + xr.w};
        *(float4*)((float*)Cv + o) = ov;
      }
    }
  }
}

// PV with MX-fp8: h_at[b] = (P[b] @ v_c[b]^T)/rsum. 64x128 tile, BK=128,
// mfma_scale_f32_16x16x128_f8f6f4 with unit e8m0 scales (127).
// Grid (4, 64, 4). Column-interleaved B-frags + bf16x4 epilogue stores.
__global__ __launch_bounds__(256) void gemm_pv_mx(
    const uint8_t* __restrict__ S, const uint8_t* __restrict__ V,
    const float* __restrict__ rsum, bf16_t* __restrict__ H) {
  __shared__ uint8_t Asm[64 * 128];
  __shared__ uint8_t Bsm[128 * 128];

  const int tid = threadIdx.x;
  const int w = tid >> 6, l = tid & 63;
  const int m0 = blockIdx.y * 64, n0 = blockIdx.x * 128;
  const int bz = blockIdx.z;

  const uint8_t* Ab = S + (long)bz * 16777216 + (long)m0 * 4096;
  const uint8_t* Bb = V + (long)bz * 4096 + (long)n0 * 16384;

  const int srow = 8 * w + (l >> 3);
  const int schunk = (l & 7) ^ (l >> 3);
  const uint8_t* ga = Ab + (long)srow * 4096 + schunk * 16;
  const uint8_t* gb = Bb + (long)srow * 16384 + schunk * 16;
  uint8_t* lA = Asm + (8 * w) * 128;
  uint8_t* lB = Bsm + (8 * w) * 128;

  const int wr = w >> 1, wc = w & 1;
  const int fr = l & 15, fq = l >> 4, l7 = l & 7;

  floatx4 acc[2][4];
#pragma unroll
  for (int i = 0; i < 2; i++)
#pragma unroll
    for (int j = 0; j < 4; j++) acc[i][j] = floatx4{0.f, 0.f, 0.f, 0.f};

  const int s0 = ((2 * fq) ^ l7) * 16;
  const int s1 = ((2 * fq + 1) ^ l7) * 16;

  for (int kb = 0; kb < 4096; kb += 128) {
#pragma unroll
    for (int p = 0; p < 4; p++) {
      if (p < 2) ld_g2l(ga + (long)p * 32 * 4096 + kb, lA + p * 4096);
      ld_g2l(gb + (long)p * 32 * 16384 + kb, lB + p * 4096);
    }
    __syncthreads();

    intx8 af[2];
#pragma unroll
    for (int mi = 0; mi < 2; mi++) {
      const uint8_t* base = Asm + (wr * 32 + mi * 16 + fr) * 128;
      uint4 x0 = *(const uint4*)(base + s0);
      uint4 x1 = *(const uint4*)(base + s1);
      af[mi] = intx8{(int)x0.x, (int)x0.y, (int)x0.z, (int)x0.w,
                     (int)x1.x, (int)x1.y, (int)x1.z, (int)x1.w};
    }
#pragma unroll
    for (int ni = 0; ni < 4; ni++) {
      const uint8_t* base = Bsm + (wc * 64 + ni + 4 * fr) * 128;  // interleave
      uint4 y0 = *(const uint4*)(base + s0);
      uint4 y1 = *(const uint4*)(base + s1);
      intx8 bf = intx8{(int)y0.x, (int)y0.y, (int)y0.z, (int)y0.w,
                       (int)y1.x, (int)y1.y, (int)y1.z, (int)y1.w};
#pragma unroll
      for (int mi = 0; mi < 2; mi++)
        acc[mi][ni] = __builtin_amdgcn_mfma_scale_f32_16x16x128_f8f6f4(
            af[mi], bf, acc[mi][ni], 0, 0, 0, 127, 0, 127);
    }
    __syncthreads();
  }

  const int rb = fq * 4;
  const int gcolb = n0 + wc * 64 + 4 * fr;
#pragma unroll
  for (int mi = 0; mi < 2; mi++) {
#pragma unroll
    for (int i = 0; i < 4; i++) {
      const int grow = m0 + wr * 32 + mi * 16 + rb + i;
      const float inv = __builtin_amdgcn_rcpf(rsum[(long)bz * PDIM + grow]);
      bf16x4 o = {(bf16_t)(acc[0][0][i] * inv), (bf16_t)(acc[0][1][i] * inv),
                  (bf16_t)(acc[0][2][i] * inv), (bf16_t)(acc[0][3][i] * inv)};
      (void)mi;
      if (mi == 1)
        o = bf16x4{(bf16_t)(acc[1][0][i] * inv), (bf16_t)(acc[1][1][i] * inv),
                   (bf16_t)(acc[1][2][i] * inv), (bf16_t)(acc[1][3][i] * inv)};
      *(bf16x4*)(H + (long)bz * (PDIM * CDIM) + (long)grow * CDIM + gcolb) = o;
    }
  }
}

// Stage 1: partial sums. Block i reads x[i*8192 .. +8192), writes (sum, sumsq).
__global__ __launch_bounds__(256) void gn_stats(const float* __restrict__ x,
                                                float2* __restrict__ part) {
  const int i = blockIdx.x;
  const float4* xp = (const float4*)(x + (long)i * 8192);
  float s0 = 0.f, s1 = 0.f;
  for (int j = threadIdx.x; j < 2048; j += 256) {
    float4 v = xp[j];
    s0 += v.x + v.y + v.z + v.w;
    s1 += v.x * v.x + v.y * v.y + v.z * v.z + v.w * v.w;
  }
  for (int o = 32; o; o >>= 1) {
    s0 += __shfl_xor(s0, o);
    s1 += __shfl_xor(s1, o);
  }
  __shared__ float r0[4], r1[4];
  if ((threadIdx.x & 63) == 0) {
    r0[threadIdx.x >> 6] = s0;
    r1[threadIdx.x >> 6] = s1;
  }
  __syncthreads();
  if (threadIdx.x == 0)
    part[i] = make_float2(r0[0] + r0[1] + r0[2] + r0[3],
                          r1[0] + r1[1] + r1[2] + r1[3]);
}

// Stage 2: normalize + transpose via LDS tile. Block = (b, 32 p-rows).
__global__ __launch_bounds__(256) void gn_norm(
    const float* __restrict__ x, const float* __restrict__ gamma,
    const float* __restrict__ beta, const float2* __restrict__ part,
    bf16_t* __restrict__ h_t) {
  const int b = blockIdx.x >> 7;
  const int p0 = (blockIdx.x & 127) * 32;
  const int t = threadIdx.x;
  __shared__ float gmS[512], btS[512];
  __shared__ float gmean[32], grstd[32];
  __shared__ __align__(16) bf16_t tile[32 * 520];

  if (t < 32) {
    const float2* pp = part + (b * 32 + t) * 8;
    float s0 = 0.f, s1 = 0.f;
#pragma unroll
    for (int s = 0; s < 8; s++) {
      float2 v = pp[s];
      s0 += v.x;
      s1 += v.y;
    }
    float mean = s0 * (1.f / 65536.f);
    float var = s1 * (1.f / 65536.f) - mean * mean;
    gmean[t] = mean;
    grstd[t] = rsqrtf(var + 1e-6f);
  }
  __syncthreads();
  for (int c = t; c < 512; c += 256) {
    float g = gamma[c] * grstd[c >> 4];
    gmS[c] = g;
    btS[c] = beta[c] - gmean[c >> 4] * g;
  }
  __syncthreads();

  const int cc = t >> 3, pcol = (t & 7) * 4;
  for (int pass = 0; pass < 16; pass++) {
    int c = pass * 32 + cc;
    float4 v = *(const float4*)(x + ((long)(b * 512 + c)) * 4096 + p0 + pcol);
    float g = gmS[c], bb = btS[c];
    tile[(pcol + 0) * 520 + c] = (bf16_t)(v.x * g + bb);
    tile[(pcol + 1) * 520 + c] = (bf16_t)(v.y * g + bb);
    tile[(pcol + 2) * 520 + c] = (bf16_t)(v.z * g + bb);
    tile[(pcol + 3) * 520 + c] = (bf16_t)(v.w * g + bb);
  }
  __syncthreads();
  const int p = t >> 3;
  bf16_t* orow = h_t + ((long)(b * 4096 + p0 + p)) * 512;
  const bf16_t* trow = tile + p * 520;
#pragma unroll
  for (int j = 0; j < 8; j++) {
    int ch = (t & 7) + 8 * j;
    *(uint4*)(orow + ch * 8) = *(const uint4*)(trow + ch * 8);
  }
}

__global__ __launch_bounds__(256) void cvt_weights(
    const float* __restrict__ wq, const float* __restrict__ wk,
    const float* __restrict__ wv, const float* __restrict__ wo,
    const float* __restrict__ bq, const float* __restrict__ bk,
    bf16_t* __restrict__ out, float* __restrict__ bqk) {
  int i = blockIdx.x * 256 + threadIdx.x;
  out[i] = (bf16_t)wq[i];
  out[262144 + i] = (bf16_t)wk[i];
  out[2 * 262144 + i] = (bf16_t)wv[i];
  out[3 * 262144 + i] = (bf16_t)wo[i];
  if (i < 512)
    bqk[i] = bq[i];
  else if (i < 1024)
    bqk[i] = bk[i - 512];
}

extern "C" void kernel_launch(void* const* d_in, const int* in_sizes, int n_in,
                              void* d_out, int out_size, void* d_ws,
                              size_t ws_size, hipStream_t stream) {
  const float* x = (const float*)d_in[0];
  const float* gamma = (const float*)d_in[1];
  const float* beta = (const float*)d_in[2];
  const float* wq = (const float*)d_in[3];
  const float* bq = (const float*)d_in[4];
  const float* wk = (const float*)d_in[5];
  const float* bk = (const float*)d_in[6];
  const float* wv = (const float*)d_in[7];
  const float* bv = (const float*)d_in[8];
  const float* wo = (const float*)d_in[9];
  const float* bo = (const float*)d_in[10];

  char* ws = (char*)d_ws;
  bf16_t* h_t = (bf16_t*)(ws);                  // [16384,512] bf16  @0
  bf16_t* qk = (bf16_t*)(ws + (16l << 20));     // [16384,1024] bf16 @16MB
  uint8_t* v_c = (uint8_t*)(ws + (48l << 20));  // [512,16384] fp8   @48MB
  bf16_t* h_at = (bf16_t*)(ws + (64l << 20));   // [16384,512] bf16  @64MB
  bf16_t* w_b = (bf16_t*)(ws + (80l << 20));    // 4x[512,512] bf16  @80MB
  float2* part = (float2*)(ws + (83l << 20));   // [1024] partials   @83MB
  float* bqk = (float*)(ws + (83l << 20) + (64l << 10));    // [1024]
  float* rsum = (float*)(ws + (83l << 20) + (128l << 10));  // [4*4096]
  uint8_t* Sbuf = (uint8_t*)(ws + (84l << 20)); // [4,4096,4096] fp8 @84MB

  const long sP = (long)PDIM * CDIM;   // 2097152
  const long sQK = (long)PDIM * 1024;  // 4194304
  const long sS = (long)PDIM * PDIM;   // 16777216
  // 1/sqrt(512) * log2(e) — EXP epilogue uses exp2
  const float qscale2 = 0.04419417382415922f * 1.4426950408889634f;

  hipMemsetAsync(rsum, 0, 4 * PDIM * sizeof(float), stream);
  cvt_weights<<<1024, 256, 0, stream>>>(wq, wk, wv, wo, bq, bk, w_b, bqk);
  gn_stats<<<1024, 256, 0, stream>>>(x, part);
  gn_norm<<<512, 256, 0, stream>>>(x, gamma, beta, part, h_t);
  // fused q|k projection: B = [wq;wk] rows 0..1023, bias bqk
  gemm_tn<EPI_QK, 128><<<dim3(8, 128, 1), 256, 0, stream>>>(
      h_t, w_b, 512, 512, 512, 0, 0, 0, qk, 1024, bqk, nullptr, nullptr, 1.0f);
  gemm_tn<EPI_V, 64><<<dim3(128, 8, 1), 256, 0, stream>>>(
      w_b + 2 * 262144, h_t, 512, 512, 512, 0, 0, 0, v_c, 16384, bv, nullptr,
      nullptr, 1.0f);
  // P = exp(q k^T / sqrt(C)) fp8 (unnormalized) + fp32 row sums into rsum
  gemm_tn<EPI_EXP, 128><<<dim3(32, 32, 4), 256, 0, stream>>>(
      qk, qk + 512, 512, 1024, 1024, sQK, sQK, sS, Sbuf, 4096, nullptr,
      nullptr, rsum, qscale2);
  // h_at = (P @ v^T) / rsum  — MX-fp8 K=128 MFMA
  gemm_pv_mx<<<dim3(4, 64, 4), 256, 0, stream>>>(Sbuf, v_c, rsum, h_at);
  gemm_tn<EPI_OUT, 64><<<dim3(128, 8, 1), 256, 0, stream>>>(
      w_b + 3 * 262144, h_at, 512, 512, 512, 0, 0, 0, d_out, 4096, bo, x,
      nullptr, 1.0f);
}

// Round 7
// 326.209 us; speedup vs baseline: 1.2594x; 1.0009x over previous
//
#include <hip/hip_runtime.h>
#include <stdint.h>

// SpatialSelfAttention: B=4, C=512, P=4096, 32 groups.
// Pipeline:
//   1. cvt weights fp32->bf16 (+ concat bq||bk); memset rsum=0
//   2. gn_stats + gn_norm -> h_t [B*P, C] bf16 (LDS tile transpose)
//   3. qk = h_t @ [wq;wk]^T  [B*P, 1024] bf16 (bias added)
//      v_c = wv @ h_t^T      [C, B*P]  fp8 e4m3
//   4. P[b] = exp(q[b] @ k[b]^T / sqrt(C))  [P,P] fp8 e4m3 (unnormalized;
//      fp32 row sums via atomics)
//   5. h_at[b] = (P[b] @ v_c[b]^T) / rsum  [P, C] bf16 via MX-scaled
//      mfma_scale_f32_16x16x128_f8f6f4 (unit scales)
//   6. out = wo @ h_at^T + bo + x  [C, B*P] fp32 == d_out layout
// Round 7: SIGMA-PERMUTED B STAGING. Round 6 changed the B-frag LDS rows
// (ni+4fr), breaking the XOR-decode invariant row&7==l&7 -> wrong k-chunks
// (absmax 4x worse, 4.2M bank conflicts). Fix: revert frag reads to the
// 0-conflict round-5 pattern (row=16ni+fr) and instead permute WHICH global
// row lands in each LDS row at staging: sigma(r)=(r&64)+4*(r&15)+((r>>4)&3).
// LDS row 16ni+fr then holds global col 4fr+ni, so each lane's 4 ni-values
// are 4 consecutive columns -> packed dword/bf16x4/float4 epilogue stores.

typedef __bf16 bf16_t;
typedef __attribute__((ext_vector_type(4))) __bf16 bf16x4;
typedef __attribute__((ext_vector_type(8))) __bf16 bf16x8;
typedef __attribute__((ext_vector_type(4))) float floatx4;
typedef __attribute__((ext_vector_type(8))) int intx8;

constexpr int CDIM = 512;
constexpr int PDIM = 4096;

__device__ __forceinline__ void ld_g2l(const void* g, void* l) {
  __builtin_amdgcn_global_load_lds(
      (const __attribute__((address_space(1))) void*)g,
      (__attribute__((address_space(3))) void*)l,
      16, 0, 0);
}

__device__ __forceinline__ uint32_t pk_fp8x4(float a, float b, float c,
                                             float d) {
  int r = __builtin_amdgcn_cvt_pk_fp8_f32(a, b, 0, false);
  r = __builtin_amdgcn_cvt_pk_fp8_f32(c, d, r, true);
  return (uint32_t)r;
}

// bijective row permutation for B staging (see header)
__device__ __forceinline__ int sigma_row(int r) {
  return (r & 64) + ((r & 15) << 2) + ((r >> 4) & 3);
}

enum { EPI_QK = 0, EPI_V = 1, EPI_EXP = 2, EPI_OUT = 4 };

// TN GEMM (bf16): C[M,N] = A[M,K] * B[N,K]^T, TMx128 tile, BK=64, 256 thr,
// 16x16x32 MFMA, sigma-staged B + packed epilogue stores.
template <int EPI, int TM>
__global__ __launch_bounds__(256) void gemm_tn(
    const bf16_t* __restrict__ A, const bf16_t* __restrict__ B, int K,
    int lda, int ldb, long sAb, long sBb, long sCb, void* __restrict__ Cv,
    int ldc, const float* __restrict__ bias, const float* __restrict__ xres,
    float* __restrict__ rsum, float scale) {
  constexpr int MI = TM / 32;
  constexpr int WROWS = TM / 2;
  __shared__ bf16_t Asm[TM * 64];
  __shared__ bf16_t Bsm[128 * 64];

  const int tid = threadIdx.x;
  const int w = tid >> 6, l = tid & 63;
  const int m0 = blockIdx.y * TM, n0 = blockIdx.x * 128;
  const int bz = blockIdx.z;

  const bf16_t* Ab = A + (long)bz * sAb + (long)m0 * lda;
  const bf16_t* Bb = B + (long)bz * sBb + (long)n0 * ldb;

  const int r0 = 8 * w + (l >> 3);
  const int schunk = (l & 7) ^ (l >> 3);
  const bf16_t* ga = Ab + (long)r0 * lda + schunk * 8;
  bf16_t* lA = Asm + (8 * w) * 64;
  bf16_t* lB = Bsm + (8 * w) * 64;

  const int wr = w >> 1, wc = w & 1;
  const int fr = l & 15, fq = l >> 4, l7 = l & 7;

  floatx4 acc[MI][4];
  floatx4 zz = {0.f, 0.f, 0.f, 0.f};
#pragma unroll
  for (int i = 0; i < MI; i++)
#pragma unroll
    for (int j = 0; j < 4; j++) acc[i][j] = zz;

  for (int kb = 0; kb < K; kb += 64) {
#pragma unroll
    for (int p = 0; p < 4; p++) {
      if (p < TM / 32) ld_g2l(ga + (long)p * 32 * lda + kb, lA + p * 2048);
      const int sig = sigma_row(r0 + 32 * p);  // B rows sigma-permuted
      ld_g2l(Bb + (long)sig * ldb + schunk * 8 + kb, lB + p * 2048);
    }
    __syncthreads();
#pragma unroll
    for (int ks = 0; ks < 2; ks++) {
      bf16x8 af[MI], bfv[4];
      const int ch = (ks * 4 + fq);
#pragma unroll
      for (int mi = 0; mi < MI; mi++) {
        int row = wr * WROWS + mi * 16 + fr;
        af[mi] = *(const bf16x8*)(Asm + row * 64 + ((ch ^ l7) * 8));
      }
#pragma unroll
      for (int ni = 0; ni < 4; ni++) {
        int row = wc * 64 + ni * 16 + fr;  // round-5 pattern: row&7 == l7
        bfv[ni] = *(const bf16x8*)(Bsm + row * 64 + ((ch ^ l7) * 8));
      }
#pragma unroll
      for (int mi = 0; mi < MI; mi++)
#pragma unroll
        for (int ni = 0; ni < 4; ni++)
          acc[mi][ni] = __builtin_amdgcn_mfma_f32_16x16x32_bf16(
              af[mi], bfv[ni], acc[mi][ni], 0, 0, 0);
    }
    __syncthreads();
  }

  // epilogue: sigma staging => MFMA ni, lane fr holds global col 4fr+ni
  const int rb = fq * 4;
  const int gcolb = n0 + wc * 64 + 4 * fr;
#pragma unroll
  for (int mi = 0; mi < MI; mi++) {
#pragma unroll
    for (int i = 0; i < 4; i++) {
      const int grow = m0 + wr * WROWS + mi * 16 + rb + i;
      float v0 = acc[mi][0][i], v1 = acc[mi][1][i];
      float v2 = acc[mi][2][i], v3 = acc[mi][3][i];
      if constexpr (EPI == EPI_QK) {
        const float4 b4 = *(const float4*)(bias + gcolb);
        bf16x4 o = {(bf16_t)(v0 + b4.x), (bf16_t)(v1 + b4.y),
                    (bf16_t)(v2 + b4.z), (bf16_t)(v3 + b4.w)};
        *(bf16x4*)((bf16_t*)Cv + (long)bz * sCb + (long)grow * ldc + gcolb) =
            o;
      } else if constexpr (EPI == EPI_V) {
        const float bb = bias[grow];
        uint32_t d = pk_fp8x4(v0 + bb, v1 + bb, v2 + bb, v3 + bb);
        *(uint32_t*)((uint8_t*)Cv + (long)bz * sCb + (long)grow * ldc +
                     gcolb) = d;
      } else if constexpr (EPI == EPI_EXP) {
        // scale = 1/sqrt(C) * log2(e); exp2 saves the inner mul
        float p0 = exp2f(v0 * scale), p1 = exp2f(v1 * scale);
        float p2 = exp2f(v2 * scale), p3 = exp2f(v3 * scale);
        *(uint32_t*)((uint8_t*)Cv + (long)bz * sCb + (long)grow * ldc +
                     gcolb) = pk_fp8x4(p0, p1, p2, p3);
        float rowacc = (p0 + p1) + (p2 + p3);
        rowacc += __shfl_xor(rowacc, 1);
        rowacc += __shfl_xor(rowacc, 2);
        rowacc += __shfl_xor(rowacc, 4);
        rowacc += __shfl_xor(rowacc, 8);
        if (fr == 0) atomicAdd(&rsum[(long)bz * PDIM + grow], rowacc);
      } else {  // EPI_OUT: grow = out channel, gcolb = b*P+p (4-aligned)
        int ob = gcolb >> 12, op = gcolb & 4095;
        long o = ((long)ob * CDIM + grow) * PDIM + op;
        const float4 xr = *(const float4*)(xres + o);
        const float bb = bias[grow];
        float4 ov = {v0 + bb + xr.x, v1 + bb + xr.y, v2 + bb + xr.z,
                     v3 + bb + xr.w};
        *(float4*)((float*)Cv + o) = ov;
      }
    }
  }
}

// PV with MX-fp8: h_at[b] = (P[b] @ v_c[b]^T)/rsum. 64x128 tile, BK=128,
// mfma_scale_f32_16x16x128_f8f6f4, unit e8m0 scales (127). Grid (4,64,4).
// sigma-staged B + bf16x4 packed stores; frag reads = round-5 pattern.
__global__ __launch_bounds__(256) void gemm_pv_mx(
    const uint8_t* __restrict__ S, const uint8_t* __restrict__ V,
    const float* __restrict__ rsum, bf16_t* __restrict__ H) {
  __shared__ uint8_t Asm[64 * 128];
  __shared__ uint8_t Bsm[128 * 128];

  const int tid = threadIdx.x;
  const int w = tid >> 6, l = tid & 63;
  const int m0 = blockIdx.y * 64, n0 = blockIdx.x * 128;
  const int bz = blockIdx.z;

  const uint8_t* Ab = S + (long)bz * 16777216 + (long)m0 * 4096;
  const uint8_t* Bb = V + (long)bz * 4096 + (long)n0 * 16384;

  const int r0 = 8 * w + (l >> 3);
  const int schunk = (l & 7) ^ (l >> 3);
  const uint8_t* ga = Ab + (long)r0 * 4096 + schunk * 16;
  uint8_t* lA = Asm + (8 * w) * 128;
  uint8_t* lB = Bsm + (8 * w) * 128;

  const int wr = w >> 1, wc = w & 1;
  const int fr = l & 15, fq = l >> 4, l7 = l & 7;

  floatx4 acc[2][4];
#pragma unroll
  for (int i = 0; i < 2; i++)
#pragma unroll
    for (int j = 0; j < 4; j++) acc[i][j] = floatx4{0.f, 0.f, 0.f, 0.f};

  const int s0 = ((2 * fq) ^ l7) * 16;
  const int s1 = ((2 * fq + 1) ^ l7) * 16;

  for (int kb = 0; kb < 4096; kb += 128) {
#pragma unroll
    for (int p = 0; p < 4; p++) {
      if (p < 2) ld_g2l(ga + (long)p * 32 * 4096 + kb, lA + p * 4096);
      const int sig = sigma_row(r0 + 32 * p);  // B rows sigma-permuted
      ld_g2l(Bb + (long)sig * 16384 + schunk * 16 + kb, lB + p * 4096);
    }
    __syncthreads();

    intx8 af[2];
#pragma unroll
    for (int mi = 0; mi < 2; mi++) {
      const uint8_t* base = Asm + (wr * 32 + mi * 16 + fr) * 128;
      uint4 x0 = *(const uint4*)(base + s0);
      uint4 x1 = *(const uint4*)(base + s1);
      af[mi] = intx8{(int)x0.x, (int)x0.y, (int)x0.z, (int)x0.w,
                     (int)x1.x, (int)x1.y, (int)x1.z, (int)x1.w};
    }
#pragma unroll
    for (int ni = 0; ni < 4; ni++) {
      const uint8_t* base = Bsm + (wc * 64 + ni * 16 + fr) * 128;  // row&7==l7
      uint4 y0 = *(const uint4*)(base + s0);
      uint4 y1 = *(const uint4*)(base + s1);
      intx8 bf = intx8{(int)y0.x, (int)y0.y, (int)y0.z, (int)y0.w,
                       (int)y1.x, (int)y1.y, (int)y1.z, (int)y1.w};
#pragma unroll
      for (int mi = 0; mi < 2; mi++)
        acc[mi][ni] = __builtin_amdgcn_mfma_scale_f32_16x16x128_f8f6f4(
            af[mi], bf, acc[mi][ni], 0, 0, 0, 127, 0, 127);
    }
    __syncthreads();
  }

  const int rb = fq * 4;
  const int gcolb = n0 + wc * 64 + 4 * fr;
#pragma unroll
  for (int mi = 0; mi < 2; mi++) {
#pragma unroll
    for (int i = 0; i < 4; i++) {
      const int grow = m0 + wr * 32 + mi * 16 + rb + i;
      const float inv = __builtin_amdgcn_rcpf(rsum[(long)bz * PDIM + grow]);
      bf16x4 o = {(bf16_t)(acc[mi][0][i] * inv), (bf16_t)(acc[mi][1][i] * inv),
                  (bf16_t)(acc[mi][2][i] * inv),
                  (bf16_t)(acc[mi][3][i] * inv)};
      *(bf16x4*)(H + (long)bz * (PDIM * CDIM) + (long)grow * CDIM + gcolb) = o;
    }
  }
}

// Stage 1: partial sums. Block i reads x[i*8192 .. +8192), writes (sum, sumsq).
__global__ __launch_bounds__(256) void gn_stats(const float* __restrict__ x,
                                                float2* __restrict__ part) {
  const int i = blockIdx.x;
  const float4* xp = (const float4*)(x + (long)i * 8192);
  float s0 = 0.f, s1 = 0.f;
  for (int j = threadIdx.x; j < 2048; j += 256) {
    float4 v = xp[j];
    s0 += v.x + v.y + v.z + v.w;
    s1 += v.x * v.x + v.y * v.y + v.z * v.z + v.w * v.w;
  }
  for (int o = 32; o; o >>= 1) {
    s0 += __shfl_xor(s0, o);
    s1 += __shfl_xor(s1, o);
  }
  __shared__ float r0[4], r1[4];
  if ((threadIdx.x & 63) == 0) {
    r0[threadIdx.x >> 6] = s0;
    r1[threadIdx.x >> 6] = s1;
  }
  __syncthreads();
  if (threadIdx.x == 0)
    part[i] = make_float2(r0[0] + r0[1] + r0[2] + r0[3],
                          r1[0] + r1[1] + r1[2] + r1[3]);
}

// Stage 2: normalize + transpose via LDS tile. Block = (b, 32 p-rows).
__global__ __launch_bounds__(256) void gn_norm(
    const float* __restrict__ x, const float* __restrict__ gamma,
    const float* __restrict__ beta, const float2* __restrict__ part,
    bf16_t* __restrict__ h_t) {
  const int b = blockIdx.x >> 7;
  const int p0 = (blockIdx.x & 127) * 32;
  const int t = threadIdx.x;
  __shared__ float gmS[512], btS[512];
  __shared__ float gmean[32], grstd[32];
  __shared__ __align__(16) bf16_t tile[32 * 520];

  if (t < 32) {
    const float2* pp = part + (b * 32 + t) * 8;
    float s0 = 0.f, s1 = 0.f;
#pragma unroll
    for (int s = 0; s < 8; s++) {
      float2 v = pp[s];
      s0 += v.x;
      s1 += v.y;
    }
    float mean = s0 * (1.f / 65536.f);
    float var = s1 * (1.f / 65536.f) - mean * mean;
    gmean[t] = mean;
    grstd[t] = rsqrtf(var + 1e-6f);
  }
  __syncthreads();
  for (int c = t; c < 512; c += 256) {
    float g = gamma[c] * grstd[c >> 4];
    gmS[c] = g;
    btS[c] = beta[c] - gmean[c >> 4] * g;
  }
  __syncthreads();

  const int cc = t >> 3, pcol = (t & 7) * 4;
  for (int pass = 0; pass < 16; pass++) {
    int c = pass * 32 + cc;
    float4 v = *(const float4*)(x + ((long)(b * 512 + c)) * 4096 + p0 + pcol);
    float g = gmS[c], bb = btS[c];
    tile[(pcol + 0) * 520 + c] = (bf16_t)(v.x * g + bb);
    tile[(pcol + 1) * 520 + c] = (bf16_t)(v.y * g + bb);
    tile[(pcol + 2) * 520 + c] = (bf16_t)(v.z * g + bb);
    tile[(pcol + 3) * 520 + c] = (bf16_t)(v.w * g + bb);
  }
  __syncthreads();
  const int p = t >> 3;
  bf16_t* orow = h_t + ((long)(b * 4096 + p0 + p)) * 512;
  const bf16_t* trow = tile + p * 520;
#pragma unroll
  for (int j = 0; j < 8; j++) {
    int ch = (t & 7) + 8 * j;
    *(uint4*)(orow + ch * 8) = *(const uint4*)(trow + ch * 8);
  }
}

__global__ __launch_bounds__(256) void cvt_weights(
    const float* __restrict__ wq, const float* __restrict__ wk,
    const float* __restrict__ wv, const float* __restrict__ wo,
    const float* __restrict__ bq, const float* __restrict__ bk,
    bf16_t* __restrict__ out, float* __restrict__ bqk) {
  int i = blockIdx.x * 256 + threadIdx.x;
  out[i] = (bf16_t)wq[i];
  out[262144 + i] = (bf16_t)wk[i];
  out[2 * 262144 + i] = (bf16_t)wv[i];
  out[3 * 262144 + i] = (bf16_t)wo[i];
  if (i < 512)
    bqk[i] = bq[i];
  else if (i < 1024)
    bqk[i] = bk[i - 512];
}

extern "C" void kernel_launch(void* const* d_in, const int* in_sizes, int n_in,
                              void* d_out, int out_size, void* d_ws,
                              size_t ws_size, hipStream_t stream) {
  const float* x = (const float*)d_in[0];
  const float* gamma = (const float*)d_in[1];
  const float* beta = (const float*)d_in[2];
  const float* wq = (const float*)d_in[3];
  const float* bq = (const float*)d_in[4];
  const float* wk = (const float*)d_in[5];
  const float* bk = (const float*)d_in[6];
  const float* wv = (const float*)d_in[7];
  const float* bv = (const float*)d_in[8];
  const float* wo = (const float*)d_in[9];
  const float* bo = (const float*)d_in[10];

  char* ws = (char*)d_ws;
  bf16_t* h_t = (bf16_t*)(ws);                  // [16384,512] bf16  @0
  bf16_t* qk = (bf16_t*)(ws + (16l << 20));     // [16384,1024] bf16 @16MB
  uint8_t* v_c = (uint8_t*)(ws + (48l << 20));  // [512,16384] fp8   @48MB
  bf16_t* h_at = (bf16_t*)(ws + (64l << 20));   // [16384,512] bf16  @64MB
  bf16_t* w_b = (bf16_t*)(ws + (80l << 20));    // 4x[512,512] bf16  @80MB
  float2* part = (float2*)(ws + (83l << 20));   // [1024] partials   @83MB
  float* bqk = (float*)(ws + (83l << 20) + (64l << 10));    // [1024]
  float* rsum = (float*)(ws + (83l << 20) + (128l << 10));  // [4*4096]
  uint8_t* Sbuf = (uint8_t*)(ws + (84l << 20)); // [4,4096,4096] fp8 @84MB

  const long sP = (long)PDIM * CDIM;   // 2097152
  const long sQK = (long)PDIM * 1024;  // 4194304
  const long sS = (long)PDIM * PDIM;   // 16777216
  // 1/sqrt(512) * log2(e) — EXP epilogue uses exp2
  const float qscale2 = 0.04419417382415922f * 1.4426950408889634f;

  hipMemsetAsync(rsum, 0, 4 * PDIM * sizeof(float), stream);
  cvt_weights<<<1024, 256, 0, stream>>>(wq, wk, wv, wo, bq, bk, w_b, bqk);
  gn_stats<<<1024, 256, 0, stream>>>(x, part);
  gn_norm<<<512, 256, 0, stream>>>(x, gamma, beta, part, h_t);
  // fused q|k projection: B = [wq;wk] rows 0..1023, bias bqk
  gemm_tn<EPI_QK, 128><<<dim3(8, 128, 1), 256, 0, stream>>>(
      h_t, w_b, 512, 512, 512, 0, 0, 0, qk, 1024, bqk, nullptr, nullptr, 1.0f);
  gemm_tn<EPI_V, 64><<<dim3(128, 8, 1), 256, 0, stream>>>(
      w_b + 2 * 262144, h_t, 512, 512, 512, 0, 0, 0, v_c, 16384, bv, nullptr,
      nullptr, 1.0f);
  // P = exp(q k^T / sqrt(C)) fp8 (unnormalized) + fp32 row sums into rsum
  gemm_tn<EPI_EXP, 128><<<dim3(32, 32, 4), 256, 0, stream>>>(
      qk, qk + 512, 512, 1024, 1024, sQK, sQK, sS, Sbuf, 4096, nullptr,
      nullptr, rsum, qscale2);
  // h_at = (P @ v^T) / rsum  — MX-fp8 K=128 MFMA
  gemm_pv_mx<<<dim3(4, 64, 4), 256, 0, stream>>>(Sbuf, v_c, rsum, h_at);
  gemm_tn<EPI_OUT, 64><<<dim3(128, 8, 1), 256, 0, stream>>>(
      w_b + 3 * 262144, h_at, 512, 512, 512, 0, 0, 0, d_out, 4096, bo, x,
      nullptr, 1.0f);
}